// Round 3
// baseline (17378.510 us; speedup 1.0000x reference)
//
#include <hip/hip_runtime.h>
#include <hip/hip_bf16.h>

#define NI 784
#define NH 1024
#define NO 10
#define BATCH 512
#define TSTEPS 100

typedef __attribute__((ext_vector_type(8))) short bf16x8;
typedef __attribute__((ext_vector_type(4))) float floatx4;

__device__ __forceinline__ float bf2f(unsigned short u) {
  union { unsigned int i; float f; } v;
  v.i = ((unsigned int)u) << 16;
  return v.f;
}

// Inspect W1 bit patterns to decide bf16 (flag=1) vs fp32 (flag=0).
// For bf16 data each u32 word's bits[14:7] are the LOW bf16 element's exponent
// (sane, ~[90,130] for N(0, 1/28) weights). For fp32 data those bits are
// mantissa bits (uniform). 64 samples, vote.
__global__ void probe_dtype_kernel(const unsigned int* __restrict__ W1bits,
                                   int* __restrict__ flag) {
  const int lane = threadIdx.x;   // 64 threads
  unsigned int w = W1bits[lane];
  unsigned int e = (w >> 7) & 0xFF;
  int sane = (e >= 90 && e <= 130) ? 1 : 0;
  unsigned long long m = __ballot(sane);
  if (lane == 0) *flag = (__popcll(m) >= 40) ? 1 : 0;
}

// ---------------- bf16-input fused kernel ----------------
__global__ __launch_bounds__(256) void fused_bf16_kernel(
    const unsigned short* __restrict__ x,
    const unsigned short* __restrict__ W1,
    const unsigned short* __restrict__ b1,
    const unsigned short* __restrict__ W2,
    const unsigned short* __restrict__ b2,
    __hip_bfloat16* __restrict__ out, long long out_size,
    const int* __restrict__ flag, int use_flag)
{
  if (use_flag && *flag != 1) return;   // wave-uniform

  const int b    = blockIdx.x;
  const int tid  = threadIdx.x;
  const int lane = tid & 63;
  const int wave = tid >> 6;

  __shared__ __align__(16) unsigned short xs[NI + 16];
  __shared__ float red[4][NO];

  float w[4][NO];
#pragma unroll
  for (int j = 0; j < 4; ++j)
#pragma unroll
    for (int o = 0; o < NO; ++o)
      w[j][o] = bf2f(W2[o * NH + tid * 4 + j]);

  float bias1[4];
#pragma unroll
  for (int j = 0; j < 4; ++j) bias1[j] = bf2f(b1[tid * 4 + j]);

  float m1[4] = {0.f, 0.f, 0.f, 0.f};
  float m2 = 0.0f, bb = 0.0f;
  if (tid < NO) bb = bf2f(b2[tid]);

  for (int t = 0; t < TSTEPS; ++t) {
    if (tid < 98)   // 98*8 = 784
      *(bf16x8*)&xs[tid * 8] = *(const bf16x8*)&x[((size_t)t * BATCH + b) * NI + tid * 8];
    __syncthreads();

    float a[NO];
#pragma unroll
    for (int o = 0; o < NO; ++o) a[o] = 0.0f;

#pragma unroll
    for (int j = 0; j < 4; ++j) {
      const unsigned short* wr = W1 + (size_t)(tid * 4 + j) * NI;
      float dot = 0.0f;
      for (int cch = 0; cch < 98; ++cch) {
        bf16x8 wv = *(const bf16x8*)&wr[cch * 8];
        bf16x8 xv = *(const bf16x8*)&xs[cch * 8];
#pragma unroll
        for (int e = 0; e < 8; ++e)
          dot = fmaf(bf2f((unsigned short)wv[e]), bf2f((unsigned short)xv[e]), dot);
      }
      float cur = dot + bias1[j];
      float mj = m1[j];
      float reset = (mj > 1.0f) ? 1.0f : 0.0f;   // reset from PREVIOUS mem1
      mj = 0.9f * mj + cur - reset;
      m1[j] = mj;
      float s = (mj > 1.0f) ? 1.0f : 0.0f;       // spike from NEW mem1
#pragma unroll
      for (int o = 0; o < NO; ++o) a[o] = fmaf(s, w[j][o], a[o]);
    }

#pragma unroll
    for (int m = 1; m <= 32; m <<= 1)
#pragma unroll
      for (int o = 0; o < NO; ++o) a[o] += __shfl_xor(a[o], m, 64);

    if (lane == 0) {
#pragma unroll
      for (int o = 0; o < NO; ++o) red[wave][o] = a[o];
    }
    __syncthreads();

    if (tid < NO) {
      float cur2 = red[0][tid] + red[1][tid] + red[2][tid] + red[3][tid] + bb;
      float reset2 = (m2 > 1.0f) ? 1.0f : 0.0f;
      m2 = 0.9f * m2 + cur2 - reset2;
      float spk2 = (m2 > 1.0f) ? 1.0f : 0.0f;
      long long idx = ((long long)t * BATCH + b) * NO + tid;
      if (idx < out_size) out[idx] = __float2bfloat16(spk2);
    }
    __syncthreads();
  }

  if (tid < NO) {
    long long idx = (long long)TSTEPS * BATCH * NO + b * NO + tid;
    if (idx < out_size) out[idx] = __float2bfloat16(m2);
  }
}

// ---------------- fp32-input fused kernel ----------------
__global__ __launch_bounds__(256) void fused_fp32_kernel(
    const float* __restrict__ x,
    const float* __restrict__ W1,
    const float* __restrict__ b1,
    const float* __restrict__ W2,
    const float* __restrict__ b2,
    float* __restrict__ out, long long out_size,
    const int* __restrict__ flag, int use_flag)
{
  if (use_flag && *flag != 0) return;   // wave-uniform

  const int b    = blockIdx.x;
  const int tid  = threadIdx.x;
  const int lane = tid & 63;
  const int wave = tid >> 6;

  __shared__ __align__(16) float xs[NI + 4];
  __shared__ float red[4][NO];

  float w[4][NO];
#pragma unroll
  for (int j = 0; j < 4; ++j)
#pragma unroll
    for (int o = 0; o < NO; ++o)
      w[j][o] = W2[o * NH + tid * 4 + j];

  float bias1[4];
#pragma unroll
  for (int j = 0; j < 4; ++j) bias1[j] = b1[tid * 4 + j];

  float m1[4] = {0.f, 0.f, 0.f, 0.f};
  float m2 = 0.0f, bb = 0.0f;
  if (tid < NO) bb = b2[tid];

  for (int t = 0; t < TSTEPS; ++t) {
    if (tid < 196)   // 196*4 = 784
      *(floatx4*)&xs[tid * 4] = *(const floatx4*)&x[((size_t)t * BATCH + b) * NI + tid * 4];
    __syncthreads();

    float a[NO];
#pragma unroll
    for (int o = 0; o < NO; ++o) a[o] = 0.0f;

#pragma unroll
    for (int j = 0; j < 4; ++j) {
      const float* wr = W1 + (size_t)(tid * 4 + j) * NI;
      float dot = 0.0f;
      for (int cch = 0; cch < 196; ++cch) {
        floatx4 wv = *(const floatx4*)&wr[cch * 4];
        floatx4 xv = *(const floatx4*)&xs[cch * 4];
#pragma unroll
        for (int e = 0; e < 4; ++e) dot = fmaf(wv[e], xv[e], dot);
      }
      float cur = dot + bias1[j];
      float mj = m1[j];
      float reset = (mj > 1.0f) ? 1.0f : 0.0f;
      mj = 0.9f * mj + cur - reset;
      m1[j] = mj;
      float s = (mj > 1.0f) ? 1.0f : 0.0f;
#pragma unroll
      for (int o = 0; o < NO; ++o) a[o] = fmaf(s, w[j][o], a[o]);
    }

#pragma unroll
    for (int m = 1; m <= 32; m <<= 1)
#pragma unroll
      for (int o = 0; o < NO; ++o) a[o] += __shfl_xor(a[o], m, 64);

    if (lane == 0) {
#pragma unroll
      for (int o = 0; o < NO; ++o) red[wave][o] = a[o];
    }
    __syncthreads();

    if (tid < NO) {
      float cur2 = red[0][tid] + red[1][tid] + red[2][tid] + red[3][tid] + bb;
      float reset2 = (m2 > 1.0f) ? 1.0f : 0.0f;
      m2 = 0.9f * m2 + cur2 - reset2;
      float spk2 = (m2 > 1.0f) ? 1.0f : 0.0f;
      long long idx = ((long long)t * BATCH + b) * NO + tid;
      if (idx < out_size) out[idx] = spk2;
    }
    __syncthreads();
  }

  if (tid < NO) {
    long long idx = (long long)TSTEPS * BATCH * NO + b * NO + tid;
    if (idx < out_size) out[idx] = m2;
  }
}

extern "C" void kernel_launch(void* const* d_in, const int* in_sizes, int n_in,
                              void* d_out, int out_size, void* d_ws, size_t ws_size,
                              hipStream_t stream) {
  const void* x  = d_in[0];
  const void* W1 = d_in[1];
  const void* b1 = d_in[2];
  const void* W2 = d_in[3];
  const void* b2 = d_in[4];

  const int have_flag = (d_ws != nullptr && ws_size >= sizeof(int)) ? 1 : 0;
  int* flag = (int*)d_ws;

  if (have_flag) {
    probe_dtype_kernel<<<1, 64, 0, stream>>>((const unsigned int*)W1, flag);
    // Launch both; each self-selects on *flag (graph-safe: same sequence
    // every call; branch is on device memory, wave-uniform).
    fused_bf16_kernel<<<BATCH, 256, 0, stream>>>(
        (const unsigned short*)x, (const unsigned short*)W1,
        (const unsigned short*)b1, (const unsigned short*)W2,
        (const unsigned short*)b2, (__hip_bfloat16*)d_out,
        (long long)out_size, flag, 1);
    fused_fp32_kernel<<<BATCH, 256, 0, stream>>>(
        (const float*)x, (const float*)W1, (const float*)b1,
        (const float*)W2, (const float*)b2, (float*)d_out,
        (long long)out_size, flag, 1);
  } else {
    // No workspace at all: assume bf16 (matches harness convention).
    fused_bf16_kernel<<<BATCH, 256, 0, stream>>>(
        (const unsigned short*)x, (const unsigned short*)W1,
        (const unsigned short*)b1, (const unsigned short*)W2,
        (const unsigned short*)b2, (__hip_bfloat16*)d_out,
        (long long)out_size, nullptr, 0);
  }
}

// Round 4
// 1341.109 us; speedup vs baseline: 12.9583x; 12.9583x over previous
//
#include <hip/hip_runtime.h>
#include <hip/hip_bf16.h>

#define NI 784
#define NH 1024
#define NO 10
#define BATCH 512
#define TSTEPS 100

#define BM 128
#define BN 128
#define BK 16
#define LDT 132   // padded LDS leading dim (132%4==0 keeps 16B alignment; breaks pow2 conflicts)

typedef __attribute__((ext_vector_type(4))) float floatx4;
typedef __attribute__((ext_vector_type(2))) float floatx2;

static __device__ __forceinline__ floatx2 fma2(floatx2 a, floatx2 b, floatx2 c) {
#if __has_builtin(__builtin_elementwise_fma)
  return __builtin_elementwise_fma(a, b, c);
#else
  floatx2 r; r.x = fmaf(a.x, b.x, c.x); r.y = fmaf(a.y, b.y, c.y); return r;
#endif
}

__global__ __launch_bounds__(256) void init_ws_kernel(float* __restrict__ p, int n) {
  int i = blockIdx.x * 256 + threadIdx.x;
  if (i < n) p[i] = 0.0f;
}

// C[M,1024] = X[M,784] @ W1[1024,784]^T + b1, all fp32.
// 128x128 tile, BK=16 (784 = 49*16, no tail). 256 threads, 8x8 outputs each.
// K-accumulation strictly sequential with fused fma -> bit-identical to the
// round-3 fused kernel's dot products (spike decisions cannot flip).
__global__ __launch_bounds__(256) void sgemm1_kernel(
    const float* __restrict__ X,
    const float* __restrict__ W1,
    const float* __restrict__ b1,
    float* __restrict__ C)
{
  __shared__ __align__(16) float As[BK * LDT];
  __shared__ __align__(16) float Bs[BK * LDT];

  const int tid = threadIdx.x;
  const int tx = tid & 15;            // n-direction (0..15)
  const int ty = tid >> 4;            // m-direction (0..15)
  const int m0 = blockIdx.y * BM;
  const int n0 = blockIdx.x * BN;     // grid.x = 8 n-blocks -> same-m blocks adjacent for L2 reuse

  const int srow  = tid >> 2;         // 0..63 staging row
  const int skcol = (tid & 3) * 4;    // 0,4,8,12 staging k-offset

  floatx2 acc[8][4];
#pragma unroll
  for (int i = 0; i < 8; ++i)
#pragma unroll
    for (int j = 0; j < 4; ++j) acc[i][j] = (floatx2){0.f, 0.f};

  for (int k0 = 0; k0 < NI; k0 += BK) {
    const floatx4 a0 = *(const floatx4*)&X [(size_t)(m0 + srow)      * NI + k0 + skcol];
    const floatx4 a1 = *(const floatx4*)&X [(size_t)(m0 + 64 + srow) * NI + k0 + skcol];
    const floatx4 w0 = *(const floatx4*)&W1[(size_t)(n0 + srow)      * NI + k0 + skcol];
    const floatx4 w1 = *(const floatx4*)&W1[(size_t)(n0 + 64 + srow) * NI + k0 + skcol];
    __syncthreads();                  // previous tile fully consumed before overwrite
#pragma unroll
    for (int e = 0; e < 4; ++e) {
      As[(skcol + e) * LDT + srow]      = a0[e];
      As[(skcol + e) * LDT + 64 + srow] = a1[e];
      Bs[(skcol + e) * LDT + srow]      = w0[e];
      Bs[(skcol + e) * LDT + 64 + srow] = w1[e];
    }
    __syncthreads();

#pragma unroll
    for (int k = 0; k < BK; ++k) {
      const floatx4 av0 = *(const floatx4*)&As[k * LDT + ty * 8];
      const floatx4 av1 = *(const floatx4*)&As[k * LDT + ty * 8 + 4];
      const floatx4 bv0 = *(const floatx4*)&Bs[k * LDT + tx * 8];
      const floatx4 bv1 = *(const floatx4*)&Bs[k * LDT + tx * 8 + 4];
      const float a[8] = {av0[0], av0[1], av0[2], av0[3], av1[0], av1[1], av1[2], av1[3]};
      const floatx2 b2[4] = {{bv0[0], bv0[1]}, {bv0[2], bv0[3]},
                             {bv1[0], bv1[1]}, {bv1[2], bv1[3]}};
#pragma unroll
      for (int i = 0; i < 8; ++i) {
        const floatx2 ai = {a[i], a[i]};
#pragma unroll
        for (int j = 0; j < 4; ++j)
          acc[i][j] = fma2(ai, b2[j], acc[i][j]);
      }
    }
  }

#pragma unroll
  for (int i = 0; i < 8; ++i) {
    float* crow = &C[(size_t)(m0 + ty * 8 + i) * NH + n0 + tx * 8];
#pragma unroll
    for (int jj = 0; jj < 2; ++jj) {
      floatx4 v;
#pragma unroll
      for (int e = 0; e < 4; ++e)
        v[e] = acc[i][jj * 2 + (e >> 1)][0 /*dummy*/] , v[e] = 0.0f; // placeholder, replaced below
      // build the 4-wide store from the two float2 accumulators + bias
      v[0] = acc[i][jj * 2 + 0].x + b1[n0 + tx * 8 + jj * 4 + 0];
      v[1] = acc[i][jj * 2 + 0].y + b1[n0 + tx * 8 + jj * 4 + 1];
      v[2] = acc[i][jj * 2 + 1].x + b1[n0 + tx * 8 + jj * 4 + 2];
      v[3] = acc[i][jj * 2 + 1].y + b1[n0 + tx * 8 + jj * 4 + 3];
      *(floatx4*)&crow[jj * 4] = v;
    }
  }
}

// One block per batch row; tc timesteps; mem1 (4 f32/thread) and mem2 (tid<10)
// in registers; W2 columns in registers. Identical math/order to the proven
// round-3 fused kernel's recurrence.
__global__ __launch_bounds__(256) void recur_kernel(
    const float* __restrict__ cur1,      // [tc*512, 1024] fp32
    const float* __restrict__ W2,        // [10,1024]
    const float* __restrict__ b2,        // [10]
    float* __restrict__ mem1s,           // [512,1024]
    float* __restrict__ mem2s,           // [512,10]
    float* __restrict__ out,             // [100*512*10 spk | 512*10 mem2]
    long long out_size, int t0, int tc, int last)
{
  const int b    = blockIdx.x;
  const int tid  = threadIdx.x;
  const int lane = tid & 63;
  const int wave = tid >> 6;

  __shared__ float red[4][NO];

  float w[4][NO];
#pragma unroll
  for (int j = 0; j < 4; ++j)
#pragma unroll
    for (int o = 0; o < NO; ++o)
      w[j][o] = W2[o * NH + tid * 4 + j];

  floatx4 m1 = *(const floatx4*)&mem1s[(size_t)b * NH + tid * 4];
  float m2 = 0.0f, bb = 0.0f;
  if (tid < NO) {
    m2 = mem2s[b * NO + tid];
    bb = b2[tid];
  }

  const floatx4* c4 = (const floatx4*)cur1;

  for (int t = 0; t < tc; ++t) {
    const floatx4 c = c4[((size_t)t * BATCH + b) * (NH / 4) + tid];

    float a[NO];
#pragma unroll
    for (int o = 0; o < NO; ++o) a[o] = 0.0f;

#pragma unroll
    for (int j = 0; j < 4; ++j) {
      float mj = m1[j];
      float reset = (mj > 1.0f) ? 1.0f : 0.0f;   // reset from PREVIOUS mem1
      mj = 0.9f * mj + c[j] - reset;
      m1[j] = mj;
      float s = (mj > 1.0f) ? 1.0f : 0.0f;       // spike from NEW mem1
#pragma unroll
      for (int o = 0; o < NO; ++o) a[o] = fmaf(s, w[j][o], a[o]);
    }

#pragma unroll
    for (int m = 1; m <= 32; m <<= 1)
#pragma unroll
      for (int o = 0; o < NO; ++o) a[o] += __shfl_xor(a[o], m, 64);

    if (lane == 0) {
#pragma unroll
      for (int o = 0; o < NO; ++o) red[wave][o] = a[o];
    }
    __syncthreads();

    if (tid < NO) {
      float cur2 = red[0][tid] + red[1][tid] + red[2][tid] + red[3][tid] + bb;
      float reset2 = (m2 > 1.0f) ? 1.0f : 0.0f;
      m2 = 0.9f * m2 + cur2 - reset2;
      float spk2 = (m2 > 1.0f) ? 1.0f : 0.0f;
      long long idx = ((long long)(t0 + t) * BATCH + b) * NO + tid;
      if (idx < out_size) out[idx] = spk2;
    }
    __syncthreads();
  }

  *(floatx4*)&mem1s[(size_t)b * NH + tid * 4] = m1;
  if (tid < NO) {
    mem2s[b * NO + tid] = m2;
    if (last) {
      long long idx = (long long)TSTEPS * BATCH * NO + b * NO + tid;
      if (idx < out_size) out[idx] = m2;
    }
  }
}

// Proven round-3 fallback (only if workspace is too small for the GEMM path).
__global__ __launch_bounds__(256) void fused_fp32_kernel(
    const float* __restrict__ x,
    const float* __restrict__ W1,
    const float* __restrict__ b1,
    const float* __restrict__ W2,
    const float* __restrict__ b2,
    float* __restrict__ out, long long out_size)
{
  const int b    = blockIdx.x;
  const int tid  = threadIdx.x;
  const int lane = tid & 63;
  const int wave = tid >> 6;

  __shared__ __align__(16) float xs[NI + 4];
  __shared__ float red[4][NO];

  float w[4][NO];
#pragma unroll
  for (int j = 0; j < 4; ++j)
#pragma unroll
    for (int o = 0; o < NO; ++o)
      w[j][o] = W2[o * NH + tid * 4 + j];

  float bias1[4];
#pragma unroll
  for (int j = 0; j < 4; ++j) bias1[j] = b1[tid * 4 + j];

  float m1[4] = {0.f, 0.f, 0.f, 0.f};
  float m2 = 0.0f, bb = 0.0f;
  if (tid < NO) bb = b2[tid];

  for (int t = 0; t < TSTEPS; ++t) {
    if (tid < 196)
      *(floatx4*)&xs[tid * 4] = *(const floatx4*)&x[((size_t)t * BATCH + b) * NI + tid * 4];
    __syncthreads();

    float a[NO];
#pragma unroll
    for (int o = 0; o < NO; ++o) a[o] = 0.0f;

#pragma unroll
    for (int j = 0; j < 4; ++j) {
      const float* wr = W1 + (size_t)(tid * 4 + j) * NI;
      float dot = 0.0f;
      for (int cch = 0; cch < 196; ++cch) {
        floatx4 wv = *(const floatx4*)&wr[cch * 4];
        floatx4 xv = *(const floatx4*)&xs[cch * 4];
#pragma unroll
        for (int e = 0; e < 4; ++e) dot = fmaf(wv[e], xv[e], dot);
      }
      float cur = dot + bias1[j];
      float mj = m1[j];
      float reset = (mj > 1.0f) ? 1.0f : 0.0f;
      mj = 0.9f * mj + cur - reset;
      m1[j] = mj;
      float s = (mj > 1.0f) ? 1.0f : 0.0f;
#pragma unroll
      for (int o = 0; o < NO; ++o) a[o] = fmaf(s, w[j][o], a[o]);
    }

#pragma unroll
    for (int m = 1; m <= 32; m <<= 1)
#pragma unroll
      for (int o = 0; o < NO; ++o) a[o] += __shfl_xor(a[o], m, 64);

    if (lane == 0) {
#pragma unroll
      for (int o = 0; o < NO; ++o) red[wave][o] = a[o];
    }
    __syncthreads();

    if (tid < NO) {
      float cur2 = red[0][tid] + red[1][tid] + red[2][tid] + red[3][tid] + bb;
      float reset2 = (m2 > 1.0f) ? 1.0f : 0.0f;
      m2 = 0.9f * m2 + cur2 - reset2;
      float spk2 = (m2 > 1.0f) ? 1.0f : 0.0f;
      long long idx = ((long long)t * BATCH + b) * NO + tid;
      if (idx < out_size) out[idx] = spk2;
    }
    __syncthreads();
  }

  if (tid < NO) {
    long long idx = (long long)TSTEPS * BATCH * NO + b * NO + tid;
    if (idx < out_size) out[idx] = m2;
  }
}

extern "C" void kernel_launch(void* const* d_in, const int* in_sizes, int n_in,
                              void* d_out, int out_size, void* d_ws, size_t ws_size,
                              hipStream_t stream) {
  const float* x  = (const float*)d_in[0];
  const float* W1 = (const float*)d_in[1];
  const float* b1 = (const float*)d_in[2];
  const float* W2 = (const float*)d_in[3];
  const float* b2 = (const float*)d_in[4];
  float* out = (float*)d_out;

  const size_t mem1_bytes = (size_t)BATCH * NH * 4;
  const size_t mem2_bytes = (size_t)BATCH * NO * 4;
  size_t fixed = (mem1_bytes + mem2_bytes + 255) & ~(size_t)255;
  const size_t per_step = (size_t)BATCH * NH * 4;   // 2 MB fp32 per timestep

  if (d_ws == nullptr || ws_size < fixed + per_step) {
    fused_fp32_kernel<<<BATCH, 256, 0, stream>>>(x, W1, b1, W2, b2, out,
                                                 (long long)out_size);
    return;
  }

  char* ws = (char*)d_ws;
  float* mem1s = (float*)ws;
  float* mem2s = (float*)(ws + mem1_bytes);
  float* cur1  = (float*)(ws + fixed);

  int Tc = (int)((ws_size - fixed) / per_step);
  if (Tc > TSTEPS) Tc = TSTEPS;

  const int nInit = BATCH * NH + BATCH * NO;
  init_ws_kernel<<<(nInit + 255) / 256, 256, 0, stream>>>((float*)ws, nInit);

  for (int t0 = 0; t0 < TSTEPS; t0 += Tc) {
    const int tc = (TSTEPS - t0 < Tc) ? (TSTEPS - t0) : Tc;
    const int M = tc * BATCH;                    // multiple of 128
    dim3 g(NH / BN, M / BM);
    sgemm1_kernel<<<g, 256, 0, stream>>>(x + (size_t)t0 * BATCH * NI, W1, b1, cur1);
    recur_kernel<<<BATCH, 256, 0, stream>>>(cur1, W2, b2, mem1s, mem2s, out,
                                            (long long)out_size, t0, tc,
                                            (t0 + tc >= TSTEPS) ? 1 : 0);
  }
}